// Round 5
// baseline (1557.423 us; speedup 1.0000x reference)
//
#include <hip/hip_runtime.h>

// ARMA GCN (K=2, two layers) on MI355X.
//   Layer1: h = mean_k relu( A@(x@iw1_k) + x@rw1_k + b1_k )   [N,16]
//   Layer2: out = mean_k relu( (A@h)@iw2_k + h@rw2_k + b2_k ) [N,40]
// - Aggregation commutes with right-multiplies: propagate 32-wide H1, 16-wide h.
// - dinv folded symmetrically: Hs = dinv*H1 (bf16), push sums then *dinv[n].
// - Edges are only coarse-partitioned by dst>>8 (256-node buckets). Props are
//   PUSH-style: one block per bucket, LDS fp32 accumulators (ds_add_f32),
//   epilogue fused in-block. No sorted CSR, no srcs array, no global atomics
//   after binA, k_final fused into prop2.
// - GEMM1 (100000x512 @ 512x64) plain bf16 MFMA (trunc-packed A via v_perm),
//   LDS/barrier-free. Error ~1e-2 vs 5.25e-2 threshold.

#define TB 256
#define TBP 1024
#define CHA 4096

typedef __attribute__((ext_vector_type(8))) short bf8;
typedef __attribute__((ext_vector_type(4))) float f4;

__device__ inline unsigned short f2bf_rne(float f) {
  unsigned int u = __float_as_uint(f);
  unsigned int r = u + 0x7fffu + ((u >> 16) & 1u);
  return (unsigned short)(r >> 16);
}
__device__ inline float bflo(unsigned int u) { return __uint_as_float(u << 16); }
__device__ inline float bfhi(unsigned int u) { return __uint_as_float(u & 0xffff0000u); }
__device__ inline unsigned int bfpack(float lo, float hi) {
  return (unsigned int)f2bf_rne(lo) | ((unsigned int)f2bf_rne(hi) << 16);
}

// ---------------- pass 0: coarse histogram (bucket = dst>>8) ----------------
__global__ __launch_bounds__(TB) void k_countA(const int* __restrict__ dst,
                                               int* __restrict__ ccnt, int E) {
  __shared__ int cnt[512];
  int tid = threadIdx.x;
  for (int i = tid; i < 512; i += TB) cnt[i] = 0;
  __syncthreads();
  int e0 = blockIdx.x * CHA;
  int e1 = min(e0 + CHA, E);
  for (int e = e0 + tid; e < e1; e += TB) atomicAdd(&cnt[dst[e] >> 8], 1);
  __syncthreads();
  for (int i = tid; i < 512; i += TB)
    if (cnt[i] > 0) atomicAdd(&ccnt[i], cnt[i]);
}

// ---------------- pass 0b: scan 512 coarse counts ----------------
__global__ __launch_bounds__(512) void k_scanC(const int* __restrict__ ccnt,
                                               int* __restrict__ cbase,
                                               int* __restrict__ ccur) {
  __shared__ int sh[512];
  int tid = threadIdx.x;
  int v = ccnt[tid];
  sh[tid] = v;
  __syncthreads();
  for (int d = 1; d < 512; d <<= 1) {
    int t = (tid >= d) ? sh[tid - d] : 0;
    __syncthreads();
    sh[tid] += t;
    __syncthreads();
  }
  int excl = sh[tid] - v;
  cbase[tid] = excl;
  ccur[tid] = excl;
  if (tid == 511) cbase[512] = sh[511];  // total = E
}

// ---------------- pass 1: partition packed edges into coarse buckets --------
// epack entry: (dst&255)<<23 | src   (src < 2^23)
__global__ __launch_bounds__(TB) void k_binA(const int* __restrict__ src,
                                             const int* __restrict__ dst,
                                             int* __restrict__ ccur,
                                             unsigned int* __restrict__ epack, int E) {
  __shared__ int cnt[512];
  __shared__ int gb[512];
  int tid = threadIdx.x;
  for (int i = tid; i < 512; i += TB) cnt[i] = 0;
  __syncthreads();
  int e0 = blockIdx.x * CHA;
  int e1 = min(e0 + CHA, E);
  for (int e = e0 + tid; e < e1; e += TB) atomicAdd(&cnt[dst[e] >> 8], 1);
  __syncthreads();
  for (int i = tid; i < 512; i += TB) {
    int c = cnt[i];
    if (c > 0) gb[i] = atomicAdd(&ccur[i], c);
    cnt[i] = 0;
  }
  __syncthreads();
  for (int e = e0 + tid; e < e1; e += TB) {
    int dv = dst[e];
    int b = dv >> 8;
    int r = atomicAdd(&cnt[b], 1);
    epack[gb[b] + r] = ((unsigned int)(dv & 255) << 23) | (unsigned int)src[e];
  }
}

// ---------------- pass 2: per-bucket degree -> dinv ----------------
__global__ __launch_bounds__(TB) void k_histd(const unsigned int* __restrict__ epack,
                                              const int* __restrict__ cbase,
                                              float* __restrict__ dinv, int N) {
  __shared__ int cnt[256];
  int b = blockIdx.x;
  int n0 = b << 8;
  int tid = threadIdx.x;
  cnt[tid] = 0;
  __syncthreads();
  int beg = cbase[b], end = cbase[b + 1];
  for (int e = beg + tid; e < end; e += TB) atomicAdd(&cnt[epack[e] >> 23], 1);
  __syncthreads();
  int n = n0 + tid;
  if (n < N) {
    int c = cnt[tid];
    dinv[n] = c > 0 ? rsqrtf((float)c) : 0.f;
  }
}

// ---------------- weight prep: fragment-ordered bf16 table ----------
// idx=((c*4+t)*64+l)*8+j -> B[k=c*32+(l>>4)*8+j][n=t*16+(l&15)],
// cols: [iw1_s0 | iw1_s1 | rw1_s0 | rw1_s1].
__global__ __launch_bounds__(TB) void k_wsplit(const float* __restrict__ iw1,
                                               const float* __restrict__ rw1,
                                               short* __restrict__ Wt) {
  int idx = blockIdx.x * TB + threadIdx.x;
  if (idx >= 32768) return;
  int j = idx & 7;
  int l = (idx >> 3) & 63;
  int t = (idx >> 9) & 3;
  int c = idx >> 11;
  int k = c * 32 + (l >> 4) * 8 + j;
  int n = t * 16 + (l & 15);
  float w;
  if (n < 16)
    w = iw1[k * 16 + n];
  else if (n < 32)
    w = iw1[8192 + k * 16 + (n - 16)];
  else if (n < 48)
    w = rw1[k * 16 + (n - 32)];
  else
    w = rw1[8192 + k * 16 + (n - 48)];
  Wt[idx] = (short)f2bf_rne(w);
}

// ---------------- GEMM1 via MFMA (plain bf16) ----------------
// Hs[N,32] bf16 = dinv[n] * x@[iw1_0|iw1_1];  R[N,32] fp32 = x@[rw1_0|rw1_1].
__global__ __launch_bounds__(TB) void k_gemm1_mfma(const float* __restrict__ x,
                                                   const short* __restrict__ Wt,
                                                   const float* __restrict__ dinv,
                                                   unsigned short* __restrict__ Hs,
                                                   float* __restrict__ R, int N) {
  int lane = threadIdx.x & 63;
  int wave = threadIdx.x >> 6;
  int row0 = blockIdx.x * 64 + wave * 16;
  int m = lane & 15, quad = lane >> 4;
  int r = row0 + m;
  bool rv = (r < N);
  const unsigned int* xr = (const unsigned int*)(x + (size_t)r * 512);

  f4 acc[4];
#pragma unroll
  for (int t = 0; t < 4; t++) acc[t] = (f4){0.f, 0.f, 0.f, 0.f};

  for (int c = 0; c < 16; ++c) {
    union { unsigned int u[4]; bf8 v; } ah;
    if (rv) {
      uint4 a0 = *(const uint4*)(xr + c * 32 + quad * 8);
      uint4 a1 = *(const uint4*)(xr + c * 32 + quad * 8 + 4);
      // pack high halves (bf16 truncation): 1 v_perm per pair
      ah.u[0] = __builtin_amdgcn_perm(a0.y, a0.x, 0x07060302u);
      ah.u[1] = __builtin_amdgcn_perm(a0.w, a0.z, 0x07060302u);
      ah.u[2] = __builtin_amdgcn_perm(a1.y, a1.x, 0x07060302u);
      ah.u[3] = __builtin_amdgcn_perm(a1.w, a1.z, 0x07060302u);
    } else {
      ah.u[0] = ah.u[1] = ah.u[2] = ah.u[3] = 0u;
    }
    const short* wb = Wt + ((size_t)(c * 4) * 64 + lane) * 8;
#pragma unroll
    for (int t = 0; t < 4; ++t) {
      bf8 bh = *(const bf8*)(wb + t * 512);
      acc[t] = __builtin_amdgcn_mfma_f32_16x16x32_bf16(ah.v, bh, acc[t], 0, 0, 0);
    }
  }
  float dv[4];
#pragma unroll
  for (int g = 0; g < 4; ++g) {
    int ro = row0 + quad * 4 + g;
    dv[g] = (ro < N) ? dinv[ro] : 0.f;
  }
#pragma unroll
  for (int t = 0; t < 4; ++t) {
#pragma unroll
    for (int g = 0; g < 4; ++g) {
      int ro = row0 + quad * 4 + g;
      if (ro < N) {
        if (t < 2)
          Hs[(size_t)ro * 32 + t * 16 + m] = f2bf_rne(acc[t][g] * dv[g]);
        else
          R[(size_t)ro * 32 + (t - 2) * 16 + m] = acc[t][g];
      }
    }
  }
}

// ---------------- prop1 push: h = mean_k relu(dinv*sum Hs[src] + R + b1) -----
// One block per 256-node bucket; LDS accum [256][33]; 4 lanes/edge x 8 feats.
__global__ __launch_bounds__(TBP) void k_prop1(const unsigned int* __restrict__ epack,
                                               const int* __restrict__ cbase,
                                               const unsigned short* __restrict__ Hs,
                                               const float* __restrict__ R,
                                               const float* __restrict__ dinv,
                                               const float* __restrict__ b1,
                                               float* __restrict__ h,
                                               unsigned short* __restrict__ hs, int N) {
  __shared__ float acc[256 * 33];
  int b = blockIdx.x;
  int n0 = b << 8;
  int tid = threadIdx.x;
  for (int i = tid; i < 256 * 33; i += TBP) acc[i] = 0.f;
  __syncthreads();
  int beg = cbase[b], end = cbase[b + 1];
  int q = tid & 3;
  for (int e = beg + (tid >> 2); e < end; e += TBP / 4) {
    unsigned int v = epack[e];
    int nl = (int)(v >> 23);
    int s = (int)(v & 0x7FFFFFu);
    uint4 hv = *(const uint4*)(Hs + (size_t)s * 32 + q * 8);
    float* a = acc + nl * 33 + q * 8;
    unsafeAtomicAdd(a + 0, bflo(hv.x)); unsafeAtomicAdd(a + 1, bfhi(hv.x));
    unsafeAtomicAdd(a + 2, bflo(hv.y)); unsafeAtomicAdd(a + 3, bfhi(hv.y));
    unsafeAtomicAdd(a + 4, bflo(hv.z)); unsafeAtomicAdd(a + 5, bfhi(hv.z));
    unsafeAtomicAdd(a + 6, bflo(hv.w)); unsafeAtomicAdd(a + 7, bfhi(hv.w));
  }
  __syncthreads();
  int n = n0 + (tid >> 2);
  if (n < N) {
    float dvn = dinv[n];
    const float* a = acc + (tid >> 2) * 33;
    f4 r0 = *(const f4*)(R + (size_t)n * 32 + q * 4);
    f4 r1 = *(const f4*)(R + (size_t)n * 32 + 16 + q * 4);
    float rr0[4] = {r0.x, r0.y, r0.z, r0.w};
    float rr1[4] = {r1.x, r1.y, r1.z, r1.w};
    float hv[4];
#pragma unroll
    for (int j = 0; j < 4; j++) {
      int f = q * 4 + j;
      float v0 = fmaxf(a[f] * dvn + rr0[j] + b1[f], 0.f);
      float v1 = fmaxf(a[f + 16] * dvn + rr1[j] + b1[16 + f], 0.f);
      hv[j] = 0.5f * (v0 + v1);
    }
    f4 ho = {hv[0], hv[1], hv[2], hv[3]};
    *(f4*)(h + (size_t)n * 16 + q * 4) = ho;
    uint2 ob;
    ob.x = bfpack(hv[0] * dvn, hv[1] * dvn);
    ob.y = bfpack(hv[2] * dvn, hv[3] * dvn);
    *(uint2*)(hs + (size_t)n * 16 + q * 4) = ob;
  }
}

// ---------------- prop2 push + fused final ----------------
// Ah = dinv*sum hs[src]; out = mean_k relu(Ah@iw2_k + h@rw2_k + b2_k)
__global__ __launch_bounds__(TBP) void k_prop2(const unsigned int* __restrict__ epack,
                                               const int* __restrict__ cbase,
                                               const unsigned short* __restrict__ hs,
                                               const float* __restrict__ h,
                                               const float* __restrict__ dinv,
                                               const float* __restrict__ iw2,
                                               const float* __restrict__ rw2,
                                               const float* __restrict__ b2,
                                               float* __restrict__ out, int N) {
  __shared__ float acc[256 * 17];
  __shared__ float wi[1280];
  __shared__ float wr[1280];
  __shared__ float wb[80];
  int b = blockIdx.x;
  int n0 = b << 8;
  int tid = threadIdx.x;
  for (int i = tid; i < 256 * 17; i += TBP) acc[i] = 0.f;
  for (int i = tid; i < 1280; i += TBP) { wi[i] = iw2[i]; wr[i] = rw2[i]; }
  if (tid < 80) wb[tid] = b2[tid];
  __syncthreads();
  int beg = cbase[b], end = cbase[b + 1];
  int q = tid & 3;
  for (int e = beg + (tid >> 2); e < end; e += TBP / 4) {
    unsigned int v = epack[e];
    int nl = (int)(v >> 23);
    int s = (int)(v & 0x7FFFFFu);
    uint2 hv = *(const uint2*)(hs + (size_t)s * 16 + q * 4);
    float* a = acc + nl * 17 + q * 4;
    unsafeAtomicAdd(a + 0, bflo(hv.x)); unsafeAtomicAdd(a + 1, bfhi(hv.x));
    unsafeAtomicAdd(a + 2, bflo(hv.y)); unsafeAtomicAdd(a + 3, bfhi(hv.y));
  }
  __syncthreads();
  int n = n0 + (tid >> 2);
  if (n < N) {
    float dvn = dinv[n];
    const float* a = acc + (tid >> 2) * 17;
    float Ahv[16], hv[16];
#pragma unroll
    for (int f = 0; f < 16; f++) Ahv[f] = a[f] * dvn;
    f4 h0 = *(const f4*)(h + (size_t)n * 16);
    f4 h1 = *(const f4*)(h + (size_t)n * 16 + 4);
    f4 h2 = *(const f4*)(h + (size_t)n * 16 + 8);
    f4 h3 = *(const f4*)(h + (size_t)n * 16 + 12);
    hv[0] = h0.x; hv[1] = h0.y; hv[2] = h0.z; hv[3] = h0.w;
    hv[4] = h1.x; hv[5] = h1.y; hv[6] = h1.z; hv[7] = h1.w;
    hv[8] = h2.x; hv[9] = h2.y; hv[10] = h2.z; hv[11] = h2.w;
    hv[12] = h3.x; hv[13] = h3.y; hv[14] = h3.z; hv[15] = h3.w;
    int o0 = q * 10;
#pragma unroll
    for (int oi = 0; oi < 10; ++oi) {
      int o = o0 + oi;
      float s0 = wb[o], s1 = wb[40 + o];
#pragma unroll
      for (int f = 0; f < 16; f++) {
        s0 += Ahv[f] * wi[f * 40 + o] + hv[f] * wr[f * 40 + o];
        s1 += Ahv[f] * wi[640 + f * 40 + o] + hv[f] * wr[640 + f * 40 + o];
      }
      out[(size_t)n * 40 + o] = 0.5f * (fmaxf(s0, 0.f) + fmaxf(s1, 0.f));
    }
  }
}

extern "C" void kernel_launch(void* const* d_in, const int* in_sizes, int n_in,
                              void* d_out, int out_size, void* d_ws, size_t ws_size,
                              hipStream_t stream) {
  const float* x = (const float*)d_in[0];
  const int* ei = (const int*)d_in[1];
  const float* iw1 = (const float*)d_in[2];
  const float* rw1 = (const float*)d_in[3];
  const float* b1 = (const float*)d_in[4];
  const float* iw2 = (const float*)d_in[5];
  const float* rw2 = (const float*)d_in[6];
  const float* b2 = (const float*)d_in[7];
  float* out = (float*)d_out;

  const int N = in_sizes[0] / 512;
  const int E = in_sizes[1] / 2;
  const int* src = ei;
  const int* dst = ei + E;
  const int NC = (N + 255) >> 8;  // 256-node buckets (<=512 for N<=131072)

  char* base = (char*)d_ws;
  size_t off = 0;
  auto alloc = [&](size_t bytes) -> void* {
    off = (off + 255) & ~(size_t)255;
    void* p = base + off;
    off += bytes;
    return p;
  };
  float* dinv = (float*)alloc((size_t)N * 4);
  int* ccnt = (int*)alloc(512 * 4);
  int* cbase = (int*)alloc(516 * 4);
  int* ccur = (int*)alloc(512 * 4);
  unsigned int* epack = (unsigned int*)alloc((size_t)E * 4);
  unsigned short* Hs = (unsigned short*)alloc((size_t)N * 32 * 2);
  float* R = (float*)alloc((size_t)N * 32 * 4);
  float* hbuf = (float*)alloc((size_t)N * 16 * 4);
  unsigned short* hs = (unsigned short*)alloc((size_t)N * 16 * 2);
  short* Wt = (short*)alloc(32768 * 2);
  (void)ws_size;

  hipMemsetAsync(ccnt, 0, 512 * 4, stream);

  int NBLK = (E + CHA - 1) / CHA;
  k_countA<<<NBLK, TB, 0, stream>>>(dst, ccnt, E);
  k_scanC<<<1, 512, 0, stream>>>(ccnt, cbase, ccur);
  k_binA<<<NBLK, TB, 0, stream>>>(src, dst, ccur, epack, E);
  k_histd<<<NC, TB, 0, stream>>>(epack, cbase, dinv, N);
  k_wsplit<<<128, TB, 0, stream>>>(iw1, rw1, Wt);
  k_gemm1_mfma<<<(N + 63) / 64, TB, 0, stream>>>(x, Wt, dinv, Hs, R, N);
  k_prop1<<<NC, TBP, 0, stream>>>(epack, cbase, Hs, R, dinv, b1, hbuf, hs, N);
  k_prop2<<<NC, TBP, 0, stream>>>(epack, cbase, hs, hbuf, dinv, iw2, rw2, b2, out, N);
}